// Round 2
// baseline (368.863 us; speedup 1.0000x reference)
//
#include <hip/hip_runtime.h>
#include <cstdint>
#include <cstddef>

// Problem constants
#define HW 512
#define NPIX (HW * HW)           // 262144 pixels per image
#define NIMG 16
#define NII 32                   // (input j, image n) pairs: ii = j*16 + n
#define CHUNKS 64
#define CHUNK_PIX 4096
#define IN_ELEMS (NIMG * NPIX)   // 4194304 per input
#define WPI 4096                 // u64 words per ii (512 rows * 8)

typedef unsigned long long u64;

// Workspace layout (bytes), total ~5.3 MB
#define WS_PARTA 0u                      // 32*64*3 doubles = 49152
#define WS_CUT   49152u                  // 32*4 floats = 512
#define WS_ZM    49664u                  // 32 u64 = 256
#define WS_PARTC 49920u                  // 32*64*2 int64 = 32768
#define WS_MP    98304u                  // marker primary bitmaps (1 MB)
#define WS_MF    (WS_MP + 1048576u)
#define WS_KP    (WS_MF + 1048576u)
#define WS_KF    (WS_KP + 1048576u)
#define WS_ROUT  (WS_KF + 1048576u)

// f64 sigmoid rounded to f32 — EXACT round-1 numerics (absmax 0.0), do not change.
__device__ __forceinline__ float sigmoid_f32(float x) {
    return (float)(1.0 / (1.0 + exp(-(double)x)));
}

// ---------------------------------------------------------------------------
// k1: read-only stats pass. f64 partial {sum, sumsq, count} of f32-rounded
// sigmoid over img>0 pixels. No output writes -> inputs stay L3-resident for k2.
__global__ void k1_stats(const float* __restrict__ A, const float* __restrict__ B,
                         double* __restrict__ partA) {
    int b = blockIdx.x;            // 0..2047
    int ii = b >> 6, chunk = b & 63;
    const float* src = ((ii >> 4) == 0 ? A : B) + (size_t)(ii & 15) * NPIX
                     + (size_t)chunk * CHUNK_PIX;
    double s = 0.0, sq = 0.0, c = 0.0;
#pragma unroll
    for (int p = 0; p < 4; ++p) {
        float4 v = *(const float4*)(src + p * 1024 + threadIdx.x * 4);
        float xs[4] = {v.x, v.y, v.z, v.w};
#pragma unroll
        for (int q = 0; q < 4; ++q) {
            float img = sigmoid_f32(xs[q]);
            if (img > 0.0f) { double d = (double)img; s += d; sq += d * d; c += 1.0; }
        }
    }
    __shared__ double sm[256], sv[256], sc[256];
    sm[threadIdx.x] = s; sv[threadIdx.x] = sq; sc[threadIdx.x] = c;
    __syncthreads();
    for (int off = 128; off > 0; off >>= 1) {
        if (threadIdx.x < off) {
            sm[threadIdx.x] += sm[threadIdx.x + off];
            sv[threadIdx.x] += sv[threadIdx.x + off];
            sc[threadIdx.x] += sc[threadIdx.x + off];
        }
        __syncthreads();
    }
    if (threadIdx.x == 0) {
        double* p = partA + (size_t)(ii * 64 + chunk) * 3;
        p[0] = sm[0]; p[1] = sv[0]; p[2] = sc[0];
    }
}

// ---------------------------------------------------------------------------
// kS: finalize stats + compute f32 logit-space cutoffs.
// cutoff(T) = smallest f32 x with sigmoid_f32(x) > T  (bisection over the
// monotone ordered-f32 key space, using the SAME f64 sigmoid -> predicates
// bit-identical to per-pixel sigmoid+compare).
__device__ __forceinline__ float key_to_f32(unsigned k) {
    unsigned b = (k & 0x80000000u) ? (k ^ 0x80000000u) : ~k;
    return __uint_as_float(b);
}
__device__ float find_cut(double T) {
    // sig(+inf)=1: if 1 <= T no x qualifies -> +inf (x >= inf is false for finite x)
    if (!(1.0 > T)) return __uint_as_float(0x7F800000u);
    unsigned lo = 0x007FFFFFu;   // key(-inf): sig=0 > T is false (T >= mean > 0)
    unsigned hi = 0xFF800000u;   // key(+inf): true
    while (lo < hi) {
        unsigned mid = lo + ((hi - lo) >> 1);
        float x = key_to_f32(mid);
        float s32 = sigmoid_f32(x);
        if ((double)s32 > T) hi = mid; else lo = mid + 1;
    }
    return key_to_f32(lo);
}

__global__ void kS_cut(const double* __restrict__ partA,
                       float* __restrict__ cut, u64* __restrict__ zm) {
    int ii = blockIdx.x, t = threadIdx.x;   // 32 blocks x 64 threads
    const double* p = partA + (size_t)(ii * 64 + t) * 3;
    double s = p[0], sq = p[1], c = p[2];
    for (int off = 32; off > 0; off >>= 1) {
        s  += __shfl_down(s,  (unsigned)off, 64);
        sq += __shfl_down(sq, (unsigned)off, 64);
        c  += __shfl_down(c,  (unsigned)off, 64);
    }
    s = __shfl(s, 0, 64); sq = __shfl(sq, 0, 64); c = __shfl(c, 0, 64);
    double mean = 0.0, sd = 0.0;
    if (c > 0.0) {
        mean = s / c;
        double var = sq / c - mean * mean;
        if (var < 0.0) var = 0.0;
        sd = sqrt(var);
    }
    double fac = (ii < 16) ? 2.0 : 4.0;
    if (t < 4) {
        double T = (t == 0) ? mean + fac * sd
                 : (t == 1) ? mean + 0.5 * fac * sd
                 : (t == 2) ? mean + 0.5 * sd
                 :            mean + 0.25 * sd;
        cut[ii * 4 + t] = find_cut(T);
    }
    if (t == 0) zm[ii] = (c > 0.0) ? ~0ull : 0ull;
}

// ---------------------------------------------------------------------------
// k2: passthrough copy + 4 candidate bitmaps via pure f32 compares + ballots.
// No per-pixel sigmoid. Reads should be mostly L3 hits (k1 warmed it).
__global__ void k2_bits(const float* __restrict__ A, const float* __restrict__ B,
                        const float* __restrict__ cut,
                        u64* __restrict__ mp, u64* __restrict__ mf,
                        u64* __restrict__ kp, u64* __restrict__ kf,
                        long long* __restrict__ partC, float* __restrict__ out) {
    int b = blockIdx.x, ii = b >> 6, chunk = b & 63;
    int j = ii >> 4, n = ii & 15;
    const float* src = (j == 0 ? A : B) + (size_t)n * NPIX;
    float* dst = out + (size_t)j * IN_ELEMS + (size_t)n * NPIX;
    float cM = cut[ii * 4 + 0], cMf = cut[ii * 4 + 1];
    float cK = cut[ii * 4 + 2], cKf = cut[ii * 4 + 3];

    int t = threadIdx.x, lane = t & 63, w = t >> 6;
    long long aM = 0, aK = 0;
#pragma unroll 4
    for (int i = 0; i < 16; ++i) {
        int e = chunk * CHUNK_PIX + i * 256 + t;
        float x = src[e];
        dst[e] = x;
        u64 bM  = __ballot(x >= cM);
        u64 bMf = __ballot(x >= cMf);
        u64 bK  = __ballot(x >= cK);
        u64 bKf = __ballot(x >= cKf);
        if (lane == 0) {
            size_t g = (size_t)ii * WPI + (size_t)chunk * 64 + i * 4 + w;
            mp[g] = bM; mf[g] = bMf; kp[g] = bK; kf[g] = bKf;
            aM += (long long)__popcll(bM);
            aK += (long long)__popcll(bK);
        }
    }
    __shared__ long long sM[4], sK[4];
    if (lane == 0) { sM[w] = aM; sK[w] = aK; }
    __syncthreads();
    if (t == 0) {
        long long* p = partC + (size_t)(ii * 64 + chunk) * 2;
        p[0] = sM[0] + sM[1] + sM[2] + sM[3];
        p[1] = sK[0] + sK[1] + sK[2] + sK[3];
    }
}

// ---------------------------------------------------------------------------
// Masked horizontal fill of a 512-bit row to FIXPOINT in O(1):
// for generators g ⊆ k, rightward fill = (~(k+g) | g) & k  (carry ripples from
// the lowest generator of each mask-run to the run end; |g restores higher
// generators; runs are isolated by zero gaps). Leftward = same on bit-reversed
// words. Both directions = complete horizontal reconstruction of the row.
__device__ __forceinline__ void hfill8(u64* x, const u64* k, u64& diff) {
    u64 f[8];
    u64 carry = 0;
#pragma unroll
    for (int w = 0; w < 8; ++w) {
        u64 a = k[w], g = x[w];
        u64 t1 = a + g;  u64 c1 = (u64)(t1 < a);
        u64 t2 = t1 + carry; u64 c2 = (u64)(t2 < t1);
        carry = c1 | c2;
        f[w] = (~t2 | g) & a;
    }
    u64 rk[8], rg[8];
#pragma unroll
    for (int w = 0; w < 8; ++w) { rk[w] = __brevll(k[7 - w]); rg[w] = __brevll(f[7 - w]); }
    carry = 0;
#pragma unroll
    for (int w = 0; w < 8; ++w) {
        u64 a = rk[w], g = rg[w];
        u64 t1 = a + g;  u64 c1 = (u64)(t1 < a);
        u64 t2 = t1 + carry; u64 c2 = (u64)(t2 < t1);
        carry = c1 | c2;
        rg[w] = (~t2 | g) & a;
    }
#pragma unroll
    for (int w = 0; w < 8; ++w) {
        u64 nx = __brevll(rg[7 - w]);
        diff |= nx ^ x[w];
        x[w] = nx;
    }
}

// ---------------------------------------------------------------------------
// k3: select (empty-fallback) + morphological reconstruction.
// 32 blocks x 128 threads; thread t owns rows 4t..4t+3 in registers.
// Per iteration: incorporate neighbor-strip inflow, Gauss-Seidel vertical
// sweeps (down+up), horizontal fixpoint per row (hfill8), sweeps again,
// boundary exchange via LDS. Terminate when block-wide no-change & no inflow.
// Monotone -> converges to the same fixpoint as the reference's Jacobi loop.
__global__ __launch_bounds__(128, 1) void k3_flood(
        const u64* __restrict__ mp, const u64* __restrict__ mf,
        const u64* __restrict__ kp, const u64* __restrict__ kf,
        const long long* __restrict__ partC, u64* __restrict__ rout) {
    int ii = blockIdx.x, t = threadIdx.x;
    __shared__ u64 btop[8 * 128], bbot[8 * 128];   // interleaved [w*128+t]
    __shared__ int ssel[2];

    if (t < 64) {
        long long a = partC[(size_t)(ii * 64 + t) * 2];
        long long b = partC[(size_t)(ii * 64 + t) * 2 + 1];
        for (int off = 32; off > 0; off >>= 1) {
            a += __shfl_down(a, (unsigned)off, 64);
            b += __shfl_down(b, (unsigned)off, 64);
        }
        if (t == 0) { ssel[0] = (a == 0); ssel[1] = (b == 0); }
    }
    __syncthreads();
    const u64* M = (ssel[0] ? mf : mp) + (size_t)ii * WPI;
    const u64* K = (ssel[1] ? kf : kp) + (size_t)ii * WPI;

    u64 r[4][8], k[4][8];
#pragma unroll
    for (int rr = 0; rr < 4; ++rr)
#pragma unroll
        for (int w = 0; w < 8; ++w) {
            k[rr][w] = K[(size_t)(t * 4 + rr) * 8 + w];
            r[rr][w] = M[(size_t)(t * 4 + rr) * 8 + w] & k[rr][w];  // marker ⊆ mask (Tm>=Tk)
        }

#pragma unroll
    for (int w = 0; w < 8; ++w) { btop[w * 128 + t] = r[0][w]; bbot[w * 128 + t] = r[3][w]; }
    __syncthreads();
    u64 nu[8], nd[8];
#pragma unroll
    for (int w = 0; w < 8; ++w) {
        nu[w] = (t > 0)   ? bbot[w * 128 + t - 1] : 0ull;
        nd[w] = (t < 127) ? btop[w * 128 + t + 1] : 0ull;
    }

    for (int it = 0; it < 2048; ++it) {
        u64 diff = 0;
#pragma unroll
        for (int w = 0; w < 8; ++w) {
            u64 a0 = nu[w] & k[0][w] & ~r[0][w]; r[0][w] |= a0; diff |= a0;
            u64 a3 = nd[w] & k[3][w] & ~r[3][w]; r[3][w] |= a3; diff |= a3;
        }
        // vertical down + up sweeps (sequential -> full strip propagation)
#pragma unroll
        for (int rr = 1; rr < 4; ++rr)
#pragma unroll
            for (int w = 0; w < 8; ++w) {
                u64 a = r[rr - 1][w] & k[rr][w] & ~r[rr][w]; r[rr][w] |= a; diff |= a;
            }
#pragma unroll
        for (int rr = 2; rr >= 0; --rr)
#pragma unroll
            for (int w = 0; w < 8; ++w) {
                u64 a = r[rr + 1][w] & k[rr][w] & ~r[rr][w]; r[rr][w] |= a; diff |= a;
            }
        // horizontal fixpoint per row
#pragma unroll
        for (int rr = 0; rr < 4; ++rr) hfill8(r[rr], k[rr], diff);
        // vertical again (carry horizontally-gained bits through the strip)
#pragma unroll
        for (int rr = 1; rr < 4; ++rr)
#pragma unroll
            for (int w = 0; w < 8; ++w) {
                u64 a = r[rr - 1][w] & k[rr][w] & ~r[rr][w]; r[rr][w] |= a; diff |= a;
            }
#pragma unroll
        for (int rr = 2; rr >= 0; --rr)
#pragma unroll
            for (int w = 0; w < 8; ++w) {
                u64 a = r[rr + 1][w] & k[rr][w] & ~r[rr][w]; r[rr][w] |= a; diff |= a;
            }
        // boundary exchange
#pragma unroll
        for (int w = 0; w < 8; ++w) { btop[w * 128 + t] = r[0][w]; bbot[w * 128 + t] = r[3][w]; }
        __syncthreads();
        u64 pend = 0;
#pragma unroll
        for (int w = 0; w < 8; ++w) {
            nu[w] = (t > 0)   ? bbot[w * 128 + t - 1] : 0ull;
            nd[w] = (t < 127) ? btop[w * 128 + t + 1] : 0ull;
            pend |= (nu[w] & k[0][w] & ~r[0][w]) | (nd[w] & k[3][w] & ~r[3][w]);
        }
        if (!__syncthreads_or((diff | pend) != 0ull ? 1 : 0)) break;
    }

#pragma unroll
    for (int rr = 0; rr < 4; ++rr)
#pragma unroll
        for (int w = 0; w < 8; ++w)
            rout[(size_t)ii * WPI + (size_t)(t * 4 + rr) * 8 + w] = r[rr][w];
}

// ---------------------------------------------------------------------------
// k4: fused output = OR of the two reconstructions (masked by cnt>0), f32 0/1.
__global__ void k4_fuse(const u64* __restrict__ rout,
                        const u64* __restrict__ zm,
                        float* __restrict__ out) {
    size_t gid = (size_t)blockIdx.x * blockDim.x + threadIdx.x;
    size_t p = gid * 4;
    int n = (int)(p >> 18);
    int e = (int)(p & (NPIX - 1));
    size_t gw = (size_t)(e >> 6);
    u64 w = (rout[(size_t)n * WPI + gw] & zm[n])
          | (rout[(size_t)(16 + n) * WPI + gw] & zm[16 + n]);
    int sh = e & 63;
    float4 v;
    v.x = ((w >> sh) & 1ull)       ? 1.0f : 0.0f;
    v.y = ((w >> (sh + 1)) & 1ull) ? 1.0f : 0.0f;
    v.z = ((w >> (sh + 2)) & 1ull) ? 1.0f : 0.0f;
    v.w = ((w >> (sh + 3)) & 1ull) ? 1.0f : 0.0f;
    *(float4*)(out + 2 * (size_t)IN_ELEMS + p) = v;
}

extern "C" void kernel_launch(void* const* d_in, const int* in_sizes, int n_in,
                              void* d_out, int out_size, void* d_ws, size_t ws_size,
                              hipStream_t stream) {
    const float* thick = (const float*)d_in[0];
    const float* thin  = (const float*)d_in[1];
    float* out = (float*)d_out;
    char* ws = (char*)d_ws;

    double*    partA = (double*)(ws + WS_PARTA);
    float*     cut   = (float*)(ws + WS_CUT);
    u64*       zm    = (u64*)(ws + WS_ZM);
    long long* partC = (long long*)(ws + WS_PARTC);
    u64*       mp    = (u64*)(ws + WS_MP);
    u64*       mf    = (u64*)(ws + WS_MF);
    u64*       kp    = (u64*)(ws + WS_KP);
    u64*       kf    = (u64*)(ws + WS_KF);
    u64*       rout  = (u64*)(ws + WS_ROUT);

    k1_stats<<<NII * CHUNKS, 256, 0, stream>>>(thick, thin, partA);
    kS_cut<<<NII, 64, 0, stream>>>(partA, cut, zm);
    k2_bits<<<NII * CHUNKS, 256, 0, stream>>>(thick, thin, cut, mp, mf, kp, kf, partC, out);
    k3_flood<<<NII, 128, 0, stream>>>(mp, mf, kp, kf, partC, rout);
    k4_fuse<<<4096, 256, 0, stream>>>(rout, zm, out);
}

// Round 3
// 151.838 us; speedup vs baseline: 2.4293x; 2.4293x over previous
//
#include <hip/hip_runtime.h>
#include <cstdint>
#include <cstddef>

// Problem constants
#define HW 512
#define NPIX (HW * HW)           // 262144 pixels per image
#define NIMG 16
#define NII 32                   // (input j, image n) pairs: ii = j*16 + n
#define CHUNKS 64
#define CHUNK_PIX 4096
#define IN_ELEMS (NIMG * NPIX)   // 4194304 per input
#define WPI 4096                 // u64 words per ii (512 rows * 8)

typedef unsigned long long u64;

// Workspace layout (bytes), total ~5.3 MB
#define WS_PARTA 0u                      // 32*64*3 doubles = 49152
#define WS_CUT   49152u                  // 32*4 floats = 512
#define WS_ZM    49664u                  // 32 u64 = 256
#define WS_PARTC 49920u                  // 32*64*2 int64 = 32768
#define WS_MP    98304u                  // marker primary bitmaps (1 MB)
#define WS_MF    (WS_MP + 1048576u)
#define WS_KP    (WS_MF + 1048576u)
#define WS_KF    (WS_KP + 1048576u)
#define WS_ROUT  (WS_KF + 1048576u)

// f64 sigmoid rounded to f32 — EXACT round-1 numerics (absmax 0.0), do not change.
__device__ __forceinline__ float sigmoid_f32(float x) {
    return (float)(1.0 / (1.0 + exp(-(double)x)));
}

// ---------------------------------------------------------------------------
// k1: read-only stats pass. f64 partial {sum, sumsq, count} of f32-rounded
// sigmoid over img>0 pixels. No output writes -> inputs stay L3-resident for k2.
__global__ void k1_stats(const float* __restrict__ A, const float* __restrict__ B,
                         double* __restrict__ partA) {
    int b = blockIdx.x;            // 0..2047
    int ii = b >> 6, chunk = b & 63;
    const float* src = ((ii >> 4) == 0 ? A : B) + (size_t)(ii & 15) * NPIX
                     + (size_t)chunk * CHUNK_PIX;
    double s = 0.0, sq = 0.0, c = 0.0;
#pragma unroll
    for (int p = 0; p < 4; ++p) {
        float4 v = *(const float4*)(src + p * 1024 + threadIdx.x * 4);
        float xs[4] = {v.x, v.y, v.z, v.w};
#pragma unroll
        for (int q = 0; q < 4; ++q) {
            float img = sigmoid_f32(xs[q]);
            if (img > 0.0f) { double d = (double)img; s += d; sq += d * d; c += 1.0; }
        }
    }
    __shared__ double sm[256], sv[256], sc[256];
    sm[threadIdx.x] = s; sv[threadIdx.x] = sq; sc[threadIdx.x] = c;
    __syncthreads();
    for (int off = 128; off > 0; off >>= 1) {
        if (threadIdx.x < off) {
            sm[threadIdx.x] += sm[threadIdx.x + off];
            sv[threadIdx.x] += sv[threadIdx.x + off];
            sc[threadIdx.x] += sc[threadIdx.x + off];
        }
        __syncthreads();
    }
    if (threadIdx.x == 0) {
        double* p = partA + (size_t)(ii * 64 + chunk) * 3;
        p[0] = sm[0]; p[1] = sv[0]; p[2] = sc[0];
    }
}

// ---------------------------------------------------------------------------
// kS: finalize stats + compute f32 logit-space cutoffs.
// cutoff(T) = smallest f32 x with sigmoid_f32(x) > T  (bisection over the
// monotone ordered-f32 key space, using the SAME f64 sigmoid -> predicates
// bit-identical to per-pixel sigmoid+compare).
__device__ __forceinline__ float key_to_f32(unsigned k) {
    unsigned b = (k & 0x80000000u) ? (k ^ 0x80000000u) : ~k;
    return __uint_as_float(b);
}
__device__ float find_cut(double T) {
    if (!(1.0 > T)) return __uint_as_float(0x7F800000u);
    unsigned lo = 0x007FFFFFu;   // key(-inf)
    unsigned hi = 0xFF800000u;   // key(+inf)
    while (lo < hi) {
        unsigned mid = lo + ((hi - lo) >> 1);
        float x = key_to_f32(mid);
        float s32 = sigmoid_f32(x);
        if ((double)s32 > T) hi = mid; else lo = mid + 1;
    }
    return key_to_f32(lo);
}

__global__ void kS_cut(const double* __restrict__ partA,
                       float* __restrict__ cut, u64* __restrict__ zm) {
    int ii = blockIdx.x, t = threadIdx.x;   // 32 blocks x 64 threads
    const double* p = partA + (size_t)(ii * 64 + t) * 3;
    double s = p[0], sq = p[1], c = p[2];
    for (int off = 32; off > 0; off >>= 1) {
        s  += __shfl_down(s,  (unsigned)off, 64);
        sq += __shfl_down(sq, (unsigned)off, 64);
        c  += __shfl_down(c,  (unsigned)off, 64);
    }
    s = __shfl(s, 0, 64); sq = __shfl(sq, 0, 64); c = __shfl(c, 0, 64);
    double mean = 0.0, sd = 0.0;
    if (c > 0.0) {
        mean = s / c;
        double var = sq / c - mean * mean;
        if (var < 0.0) var = 0.0;
        sd = sqrt(var);
    }
    double fac = (ii < 16) ? 2.0 : 4.0;
    if (t < 4) {
        double T = (t == 0) ? mean + fac * sd
                 : (t == 1) ? mean + 0.5 * fac * sd
                 : (t == 2) ? mean + 0.5 * sd
                 :            mean + 0.25 * sd;
        cut[ii * 4 + t] = find_cut(T);
    }
    if (t == 0) zm[ii] = (c > 0.0) ? ~0ull : 0ull;
}

// ---------------------------------------------------------------------------
// k2: passthrough copy + 4 candidate bitmaps via pure f32 compares + ballots.
__global__ void k2_bits(const float* __restrict__ A, const float* __restrict__ B,
                        const float* __restrict__ cut,
                        u64* __restrict__ mp, u64* __restrict__ mf,
                        u64* __restrict__ kp, u64* __restrict__ kf,
                        long long* __restrict__ partC, float* __restrict__ out) {
    int b = blockIdx.x, ii = b >> 6, chunk = b & 63;
    int j = ii >> 4, n = ii & 15;
    const float* src = (j == 0 ? A : B) + (size_t)n * NPIX;
    float* dst = out + (size_t)j * IN_ELEMS + (size_t)n * NPIX;
    float cM = cut[ii * 4 + 0], cMf = cut[ii * 4 + 1];
    float cK = cut[ii * 4 + 2], cKf = cut[ii * 4 + 3];

    int t = threadIdx.x, lane = t & 63, w = t >> 6;
    long long aM = 0, aK = 0;
#pragma unroll 4
    for (int i = 0; i < 16; ++i) {
        int e = chunk * CHUNK_PIX + i * 256 + t;
        float x = src[e];
        dst[e] = x;
        u64 bM  = __ballot(x >= cM);
        u64 bMf = __ballot(x >= cMf);
        u64 bK  = __ballot(x >= cK);
        u64 bKf = __ballot(x >= cKf);
        if (lane == 0) {
            size_t g = (size_t)ii * WPI + (size_t)chunk * 64 + i * 4 + w;
            mp[g] = bM; mf[g] = bMf; kp[g] = bK; kf[g] = bKf;
            aM += (long long)__popcll(bM);
            aK += (long long)__popcll(bK);
        }
    }
    __shared__ long long sM[4], sK[4];
    if (lane == 0) { sM[w] = aM; sK[w] = aK; }
    __syncthreads();
    if (t == 0) {
        long long* p = partC + (size_t)(ii * 64 + chunk) * 2;
        p[0] = sM[0] + sM[1] + sM[2] + sM[3];
        p[1] = sK[0] + sK[1] + sK[2] + sK[3];
    }
}

// ---------------------------------------------------------------------------
// Masked horizontal fill of a 512-bit row to FIXPOINT in O(1) (identity
// validated bit-exact in round 2): for generators g ⊆ k, rightward fill =
// (~(k+g) | g) & k; leftward = same on bit-reversed words. Lean in-place
// version: single running carry, backward pass reverses words on the fly ->
// live set stays ~r[8]+k[8]+3 temps (no spills).
__device__ __forceinline__ void hfill8(u64* x, const u64* k) {
    u64 c = 0;
#pragma unroll
    for (int w = 0; w < 8; ++w) {
        u64 a = k[w], g = x[w];
        u64 t1 = a + g;  u64 c1 = (u64)(t1 < a);
        u64 t2 = t1 + c; u64 c2 = (u64)(t2 < t1);
        c = c1 | c2;
        x[w] = (~t2 | g) & a;
    }
    c = 0;
#pragma unroll
    for (int w = 7; w >= 0; --w) {
        u64 a = __brevll(k[w]), g = __brevll(x[w]);
        u64 t1 = a + g;  u64 c1 = (u64)(t1 < a);
        u64 t2 = t1 + c; u64 c2 = (u64)(t2 < t1);
        c = c1 | c2;
        x[w] = __brevll((~t2 | g) & a);
    }
}

// ---------------------------------------------------------------------------
// k3: select (empty-fallback) + morphological reconstruction.
// 32 blocks x 512 threads (8 waves); thread t owns row t in registers, image
// bitmap mirrored in LDS (word-interleaved R[w*512+row]: consecutive lanes ->
// consecutive 8B words, conflict-free). Per iteration: Jacobi vertical OR from
// LDS neighbors; rows that gained bits run hfill8 (horizontal fixpoint) and
// write back. Converged when no row has a vertical gain (horizontal is always
// at fixpoint). Monotone -> same fixpoint as the reference's Jacobi loop.
__global__ __launch_bounds__(512) void k3_flood(
        const u64* __restrict__ mp, const u64* __restrict__ mf,
        const u64* __restrict__ kp, const u64* __restrict__ kf,
        const long long* __restrict__ partC, u64* __restrict__ rout) {
    int ii = blockIdx.x, t = threadIdx.x;   // t = row index
    __shared__ u64 R[8 * HW];               // 32 KB
    __shared__ int ssel[2];

    if (t < 64) {
        long long a = partC[(size_t)(ii * 64 + t) * 2];
        long long b = partC[(size_t)(ii * 64 + t) * 2 + 1];
        for (int off = 32; off > 0; off >>= 1) {
            a += __shfl_down(a, (unsigned)off, 64);
            b += __shfl_down(b, (unsigned)off, 64);
        }
        if (t == 0) { ssel[0] = (a == 0); ssel[1] = (b == 0); }
    }
    __syncthreads();
    const u64* M = (ssel[0] ? mf : mp) + (size_t)ii * WPI;
    const u64* K = (ssel[1] ? kf : kp) + (size_t)ii * WPI;

    u64 r[8], k[8];
#pragma unroll
    for (int w = 0; w < 8; ++w) {
        k[w] = K[(size_t)t * 8 + w];
        r[w] = M[(size_t)t * 8 + w] & k[w];   // marker ⊆ mask (Tm >= Tk always)
    }
    hfill8(r, k);                              // initial horizontal fixpoint
#pragma unroll
    for (int w = 0; w < 8; ++w) R[w * HW + t] = r[w];
    __syncthreads();

    for (int it = 0; it < 1024; ++it) {
        u64 up[8], dn[8];
#pragma unroll
        for (int w = 0; w < 8; ++w) {
            up[w] = (t > 0)      ? R[w * HW + (t - 1)] : 0ull;
            dn[w] = (t < HW - 1) ? R[w * HW + (t + 1)] : 0ull;
        }
        __syncthreads();   // all reads of old R done before any write
        u64 diff = 0;
#pragma unroll
        for (int w = 0; w < 8; ++w) {
            u64 g = (up[w] | dn[w]) & k[w] & ~r[w];
            r[w] |= g; diff |= g;
        }
        if (diff) {        // uniform-false waves skip entirely (s_cbranch_execz)
            hfill8(r, k);
#pragma unroll
            for (int w = 0; w < 8; ++w) R[w * HW + t] = r[w];
        }
        if (!__syncthreads_or(diff != 0ull ? 1 : 0)) break;
    }

    // word-interleaved output: per w, 64 lanes store 512 contiguous bytes
#pragma unroll
    for (int w = 0; w < 8; ++w)
        rout[(size_t)ii * WPI + (size_t)w * HW + t] = r[w];
}

// ---------------------------------------------------------------------------
// k4: fused output = OR of the two reconstructions (masked by cnt>0), f32 0/1.
// rout layout is word-interleaved: idx = w*512 + row.
__global__ void k4_fuse(const u64* __restrict__ rout,
                        const u64* __restrict__ zm,
                        float* __restrict__ out) {
    size_t gid = (size_t)blockIdx.x * blockDim.x + threadIdx.x;
    size_t p = gid * 4;
    int n = (int)(p >> 18);
    int e = (int)(p & (NPIX - 1));
    size_t gw = (size_t)(((e >> 6) & 7) * HW + (e >> 9));
    u64 w = (rout[(size_t)n * WPI + gw] & zm[n])
          | (rout[(size_t)(16 + n) * WPI + gw] & zm[16 + n]);
    int sh = e & 63;
    float4 v;
    v.x = ((w >> sh) & 1ull)       ? 1.0f : 0.0f;
    v.y = ((w >> (sh + 1)) & 1ull) ? 1.0f : 0.0f;
    v.z = ((w >> (sh + 2)) & 1ull) ? 1.0f : 0.0f;
    v.w = ((w >> (sh + 3)) & 1ull) ? 1.0f : 0.0f;
    *(float4*)(out + 2 * (size_t)IN_ELEMS + p) = v;
}

extern "C" void kernel_launch(void* const* d_in, const int* in_sizes, int n_in,
                              void* d_out, int out_size, void* d_ws, size_t ws_size,
                              hipStream_t stream) {
    const float* thick = (const float*)d_in[0];
    const float* thin  = (const float*)d_in[1];
    float* out = (float*)d_out;
    char* ws = (char*)d_ws;

    double*    partA = (double*)(ws + WS_PARTA);
    float*     cut   = (float*)(ws + WS_CUT);
    u64*       zm    = (u64*)(ws + WS_ZM);
    long long* partC = (long long*)(ws + WS_PARTC);
    u64*       mp    = (u64*)(ws + WS_MP);
    u64*       mf    = (u64*)(ws + WS_MF);
    u64*       kp    = (u64*)(ws + WS_KP);
    u64*       kf    = (u64*)(ws + WS_KF);
    u64*       rout  = (u64*)(ws + WS_ROUT);

    k1_stats<<<NII * CHUNKS, 256, 0, stream>>>(thick, thin, partA);
    kS_cut<<<NII, 64, 0, stream>>>(partA, cut, zm);
    k2_bits<<<NII * CHUNKS, 256, 0, stream>>>(thick, thin, cut, mp, mf, kp, kf, partC, out);
    k3_flood<<<NII, 512, 0, stream>>>(mp, mf, kp, kf, partC, rout);
    k4_fuse<<<4096, 256, 0, stream>>>(rout, zm, out);
}

// Round 5
// 145.669 us; speedup vs baseline: 2.5322x; 1.0423x over previous
//
#include <hip/hip_runtime.h>
#include <cstdint>
#include <cstddef>

// Problem constants
#define HW 512
#define NPIX (HW * HW)           // 262144 pixels per image
#define NIMG 16
#define NII 32                   // (input j, image n) pairs: ii = j*16 + n
#define CHUNKS 64
#define CHUNK_PIX 4096
#define IN_ELEMS (NIMG * NPIX)   // 4194304 per input
#define WPI 4096                 // u64 words per ii (512 rows * 8)

typedef unsigned long long u64;

// Workspace layout (bytes), total ~3.2 MB
#define WS_PARTA 0u                      // 32*64 entries * 4 doubles = 65536
#define WS_CUT   65536u                  // 32*2 floats (final cutoffs)
#define WS_ZM    65792u                  // 32 u64
#define WS_MSEL  98304u                  // selected marker bitmaps (1 MB)
#define WS_KSEL  (WS_MSEL + 1048576u)    // selected mask bitmaps (1 MB)
#define WS_ROUT  (WS_KSEL + 1048576u)    // reconstruction result (1 MB)

// f64 sigmoid rounded to f32 — EXACT round-1 numerics. Used ONLY in find_cut
// (bisection), so cutoffs stay bit-identical to the R1-R3 passing versions.
__device__ __forceinline__ float sigmoid_f32(float x) {
    return (float)(1.0 / (1.0 + exp(-(double)x)));
}

// Fast f64 sigmoid for the STATS ONLY (sum/sumsq/count). Rel error ~1e-14 ->
// shifts mean/std by ~1e-13, i.e. ~6 orders below the threshold-straddle
// margin; f32-rounded output matches libm path except ~1-in-3e6 pixels off by
// 1 ulp (negligible in a 262144-pixel f64 sum). exp(-x) = 2^y, y = -x*log2(e);
// degree-11 Taylor on the reduced argument, single bit-trick scale.
__device__ __forceinline__ float sigmoid_fast(float xf) {
    double x = (double)xf;
    double y = x * -1.4426950408889634074;     // log2(e)
    if (y > 1000.0)  return 0.0f;              // exp(-x) >= 2^1000 -> f32 0
    if (y < -1000.0) return 1.0f;              // exp(-x) <= 2^-1000 -> f32 1
    double n = __builtin_rint(y);
    double t = (y - n) * 0.69314718055994530942;   // |t| <= 0.3466
    double p = 2.5052108385441718775e-8;
    p = __builtin_fma(p, t, 2.7557319223985890653e-7);
    p = __builtin_fma(p, t, 2.7557319223985892511e-6);
    p = __builtin_fma(p, t, 2.4801587301587301566e-5);
    p = __builtin_fma(p, t, 1.9841269841269841253e-4);
    p = __builtin_fma(p, t, 1.3888888888888889419e-3);
    p = __builtin_fma(p, t, 8.3333333333333332177e-3);
    p = __builtin_fma(p, t, 4.1666666666666664354e-2);
    p = __builtin_fma(p, t, 1.6666666666666665741e-1);
    p = __builtin_fma(p, t, 5.0e-1);
    p = __builtin_fma(p, t, 1.0);
    p = __builtin_fma(p, t, 1.0);
    long long bits = ((long long)n + 1023ll) << 52;
    double e = p * __longlong_as_double(bits);     // exp(-x)
    return (float)(1.0 / (1.0 + e));
}

// ---------------------------------------------------------------------------
// k1: single input pass — passthrough copy (float4) + f64 partial
// {sum, sumsq, count} of sigmoid over img>0 pixels + per-chunk max(x).
__global__ void k1_copy_stats(const float* __restrict__ A, const float* __restrict__ B,
                              float* __restrict__ out, double* __restrict__ partA) {
    int b = blockIdx.x;            // 0..2047
    int ii = b >> 6, chunk = b & 63;
    int j = ii >> 4, n = ii & 15;
    const float* src = (j == 0 ? A : B) + (size_t)n * NPIX + (size_t)chunk * CHUNK_PIX;
    float* dst = out + (size_t)j * IN_ELEMS + (size_t)n * NPIX + (size_t)chunk * CHUNK_PIX;

    double s = 0.0, sq = 0.0, cc = 0.0;
    float mx = -__builtin_inff();
#pragma unroll
    for (int p = 0; p < 4; ++p) {
        float4 v = *(const float4*)(src + p * 1024 + threadIdx.x * 4);
        *(float4*)(dst + p * 1024 + threadIdx.x * 4) = v;
        float xs[4] = {v.x, v.y, v.z, v.w};
#pragma unroll
        for (int q = 0; q < 4; ++q) {
            float img = sigmoid_fast(xs[q]);
            mx = fmaxf(mx, xs[q]);
            if (img > 0.0f) { double d = (double)img; s += d; sq += d * d; cc += 1.0; }
        }
    }
    __shared__ double sm[256], sv[256], sc[256];
    __shared__ float smx[256];
    sm[threadIdx.x] = s; sv[threadIdx.x] = sq; sc[threadIdx.x] = cc; smx[threadIdx.x] = mx;
    __syncthreads();
    for (int off = 128; off > 0; off >>= 1) {
        if (threadIdx.x < off) {
            sm[threadIdx.x] += sm[threadIdx.x + off];
            sv[threadIdx.x] += sv[threadIdx.x + off];
            sc[threadIdx.x] += sc[threadIdx.x + off];
            smx[threadIdx.x] = fmaxf(smx[threadIdx.x], smx[threadIdx.x + off]);
        }
        __syncthreads();
    }
    if (threadIdx.x == 0) {
        double* p = partA + (size_t)(ii * 64 + chunk) * 4;
        p[0] = sm[0]; p[1] = sv[0]; p[2] = sc[0]; p[3] = (double)smx[0];
    }
}

// ---------------------------------------------------------------------------
// kS: finalize stats, bisect the 4 candidate cutoffs (bit-identical libm
// sigmoid), resolve the empty-fallback via max(x) (count(x>=cut)==0 <=>
// max(x) < cut), emit the 2 FINAL cutoffs + zero-mask.
__device__ __forceinline__ float key_to_f32(unsigned k) {
    unsigned b = (k & 0x80000000u) ? (k ^ 0x80000000u) : ~k;
    return __uint_as_float(b);
}
__device__ float find_cut(double T) {
    if (!(1.0 > T)) return __uint_as_float(0x7F800000u);
    unsigned lo = 0x007FFFFFu;   // key(-inf)
    unsigned hi = 0xFF800000u;   // key(+inf)
    while (lo < hi) {
        unsigned mid = lo + ((hi - lo) >> 1);
        float x = key_to_f32(mid);
        float s32 = sigmoid_f32(x);
        if ((double)s32 > T) hi = mid; else lo = mid + 1;
    }
    return key_to_f32(lo);
}

__global__ void kS_cut(const double* __restrict__ partA,
                       float* __restrict__ cut2, u64* __restrict__ zm) {
    int ii = blockIdx.x, t = threadIdx.x;   // 32 blocks x 64 threads
    const double* p = partA + (size_t)(ii * 64 + t) * 4;
    double s = p[0], sq = p[1], c = p[2], mx = p[3];
    for (int off = 32; off > 0; off >>= 1) {
        s  += __shfl_down(s,  (unsigned)off, 64);
        sq += __shfl_down(sq, (unsigned)off, 64);
        c  += __shfl_down(c,  (unsigned)off, 64);
        mx  = fmax(mx, __shfl_down(mx, (unsigned)off, 64));
    }
    s = __shfl(s, 0, 64); sq = __shfl(sq, 0, 64);
    c = __shfl(c, 0, 64); mx = __shfl(mx, 0, 64);
    double mean = 0.0, sd = 0.0;
    if (c > 0.0) {
        mean = s / c;
        double var = sq / c - mean * mean;
        if (var < 0.0) var = 0.0;
        sd = sqrt(var);
    }
    double fac = (ii < 16) ? 2.0 : 4.0;
    __shared__ float cs[4];
    if (t < 4) {
        double T = (t == 0) ? mean + fac * sd
                 : (t == 1) ? mean + 0.5 * fac * sd
                 : (t == 2) ? mean + 0.5 * sd
                 :            mean + 0.25 * sd;
        cs[t] = find_cut(T);
    }
    __syncthreads();
    if (t == 0) {
        float mxf = (float)mx;
        cut2[ii * 2 + 0] = (mxf >= cs[0]) ? cs[0] : cs[1];  // marker: primary unless empty
        cut2[ii * 2 + 1] = (mxf >= cs[2]) ? cs[2] : cs[3];  // mask
        zm[ii] = (c > 0.0) ? ~0ull : 0ull;
    }
}

// ---------------------------------------------------------------------------
// k2: selected marker+mask bitmaps via pure f32 compares + ballots.
// Inputs are L3-warm from k1; writes only 2 MB.
__global__ void k2_bits(const float* __restrict__ A, const float* __restrict__ B,
                        const float* __restrict__ cut2,
                        u64* __restrict__ msel, u64* __restrict__ ksel) {
    int b = blockIdx.x, ii = b >> 6, chunk = b & 63;
    int j = ii >> 4, n = ii & 15;
    const float* src = (j == 0 ? A : B) + (size_t)n * NPIX;
    float cM = cut2[ii * 2 + 0];
    float cK = cut2[ii * 2 + 1];
    int t = threadIdx.x, lane = t & 63, w = t >> 6;
#pragma unroll 4
    for (int i = 0; i < 16; ++i) {
        float x = src[chunk * CHUNK_PIX + i * 256 + t];
        u64 bM = __ballot(x >= cM);
        u64 bK = __ballot(x >= cK);
        if (lane == 0) {
            size_t g = (size_t)ii * WPI + (size_t)chunk * 64 + i * 4 + w;
            msel[g] = bM; ksel[g] = bK;
        }
    }
}

// ---------------------------------------------------------------------------
// Masked horizontal fill of a 512-bit row to FIXPOINT in O(1) (proven R2/R3):
// rightward fill of generators g within mask k = (~(k+g) | g) & k; leftward =
// same on bit-reversed words. In-place, single running carry -> no spills.
__device__ __forceinline__ void hfill8(u64* x, const u64* k) {
    u64 c = 0;
#pragma unroll
    for (int w = 0; w < 8; ++w) {
        u64 a = k[w], g = x[w];
        u64 t1 = a + g;  u64 c1 = (u64)(t1 < a);
        u64 t2 = t1 + c; u64 c2 = (u64)(t2 < t1);
        c = c1 | c2;
        x[w] = (~t2 | g) & a;
    }
    c = 0;
#pragma unroll
    for (int w = 7; w >= 0; --w) {
        u64 a = __brevll(k[w]), g = __brevll(x[w]);
        u64 t1 = a + g;  u64 c1 = (u64)(t1 < a);
        u64 t2 = t1 + c; u64 c2 = (u64)(t2 < t1);
        c = c1 | c2;
        x[w] = __brevll((~t2 | g) & a);
    }
}

// ---------------------------------------------------------------------------
// k3: morphological reconstruction (structure proven in R3).
// 32 blocks x 512 threads; thread t owns row t in registers, image bitmap
// mirrored in LDS (word-interleaved: conflict-free). Jacobi vertical OR +
// hfill8 horizontal fixpoint on rows that gained bits.
__global__ __launch_bounds__(512) void k3_flood(const u64* __restrict__ msel,
                                                const u64* __restrict__ ksel,
                                                u64* __restrict__ rout) {
    int ii = blockIdx.x, t = threadIdx.x;   // t = row index
    __shared__ u64 R[8 * HW];               // 32 KB
    const u64* M = msel + (size_t)ii * WPI;
    const u64* K = ksel + (size_t)ii * WPI;

    u64 r[8], k[8];
#pragma unroll
    for (int w = 0; w < 8; ++w) {
        k[w] = K[(size_t)t * 8 + w];
        r[w] = M[(size_t)t * 8 + w] & k[w];   // marker ⊆ mask (Tm >= Tk always)
    }
    hfill8(r, k);                              // initial horizontal fixpoint
#pragma unroll
    for (int w = 0; w < 8; ++w) R[w * HW + t] = r[w];
    __syncthreads();

    for (int it = 0; it < 1024; ++it) {
        u64 up[8], dn[8];
#pragma unroll
        for (int w = 0; w < 8; ++w) {
            up[w] = (t > 0)      ? R[w * HW + (t - 1)] : 0ull;
            dn[w] = (t < HW - 1) ? R[w * HW + (t + 1)] : 0ull;
        }
        __syncthreads();
        u64 diff = 0;
#pragma unroll
        for (int w = 0; w < 8; ++w) {
            u64 g = (up[w] | dn[w]) & k[w] & ~r[w];
            r[w] |= g; diff |= g;
        }
        if (diff) {        // uniform-false waves skip entirely
            hfill8(r, k);
#pragma unroll
            for (int w = 0; w < 8; ++w) R[w * HW + t] = r[w];
        }
        if (!__syncthreads_or(diff != 0ull ? 1 : 0)) break;
    }

    // word-interleaved output: per w, 64 lanes store 512 contiguous bytes
#pragma unroll
    for (int w = 0; w < 8; ++w)
        rout[(size_t)ii * WPI + (size_t)w * HW + t] = r[w];
}

// ---------------------------------------------------------------------------
// k4: fused output = OR of the two reconstructions (masked by cnt>0), f32 0/1.
// rout layout is word-interleaved: idx = w*512 + row.
__global__ void k4_fuse(const u64* __restrict__ rout,
                        const u64* __restrict__ zm,
                        float* __restrict__ out) {
    size_t gid = (size_t)blockIdx.x * blockDim.x + threadIdx.x;
    size_t p = gid * 4;
    int n = (int)(p >> 18);
    int e = (int)(p & (NPIX - 1));
    size_t gw = (size_t)(((e >> 6) & 7) * HW + (e >> 9));
    u64 w = (rout[(size_t)n * WPI + gw] & zm[n])
          | (rout[(size_t)(16 + n) * WPI + gw] & zm[16 + n]);
    int sh = e & 63;
    float4 v;
    v.x = ((w >> sh) & 1ull)       ? 1.0f : 0.0f;
    v.y = ((w >> (sh + 1)) & 1ull) ? 1.0f : 0.0f;
    v.z = ((w >> (sh + 2)) & 1ull) ? 1.0f : 0.0f;
    v.w = ((w >> (sh + 3)) & 1ull) ? 1.0f : 0.0f;
    *(float4*)(out + 2 * (size_t)IN_ELEMS + p) = v;
}

extern "C" void kernel_launch(void* const* d_in, const int* in_sizes, int n_in,
                              void* d_out, int out_size, void* d_ws, size_t ws_size,
                              hipStream_t stream) {
    const float* A = (const float*)d_in[0];
    const float* B = (const float*)d_in[1];
    float* out = (float*)d_out;
    char* ws = (char*)d_ws;

    double* partA = (double*)(ws + WS_PARTA);
    float*  cut2  = (float*)(ws + WS_CUT);
    u64*    zm    = (u64*)(ws + WS_ZM);
    u64*    msel  = (u64*)(ws + WS_MSEL);
    u64*    ksel  = (u64*)(ws + WS_KSEL);
    u64*    rout  = (u64*)(ws + WS_ROUT);

    k1_copy_stats<<<NII * CHUNKS, 256, 0, stream>>>(A, B, out, partA);
    kS_cut<<<NII, 64, 0, stream>>>(partA, cut2, zm);
    k2_bits<<<NII * CHUNKS, 256, 0, stream>>>(A, B, cut2, msel, ksel);
    k3_flood<<<NII, 512, 0, stream>>>(msel, ksel, rout);
    k4_fuse<<<4096, 256, 0, stream>>>(rout, zm, out);
}